// Round 11
// baseline (420.776 us; speedup 1.0000x reference)
//
#include <hip/hip_runtime.h>
#include <cstdint>
#include <cstddef>

#define B_ 512
#define W_ 1024
#define L_ 64
#define J_ 8
#define I_ 32
#define O_ 128
#define H_ 8            // wm split: 8 blocks of 128 rows each (8*128 = 1024 = W ✓)

// ws layout (floats):
// wcg   : [J][L]        = 512   (holds -2*(1-g)*c)
// w1g   : [J][L]        = 512
// Ag    : [J] (+pad)    = 16
// best  : [J][B][L]     = 262144
// conf  : [B]           = 512
// partial:[64][B][I]    = 1048576
// bpart : [H][J][B][L]  = 2097152
// stats : [H][B][J][4]  = 65536

// ---------------------------------------------------------------- K0
__global__ __launch_bounds__(64) void k0_prep(const float* __restrict__ constants,
    const float* __restrict__ gammas, float* __restrict__ wcg,
    float* __restrict__ w1g, float* __restrict__ Ag)
{
  const int l = threadIdx.x;
  #pragma unroll
  for (int j = 0; j < J_; ++j) {
    float g = gammas[j*L_ + l];
    g = fminf(fmaxf(g, 0.f), 1.f);
    float c = constants[j*L_ + l];
    float w1 = 1.f - g;
    w1g[j*L_ + l] = w1;
    wcg[j*L_ + l] = -2.f * w1 * c;   // fold the -2 of the cross term here
  }
  if (l < J_) {
    float a = 0.f;
    for (int c = 0; c < L_; ++c) {
      float g = gammas[l*L_ + c];
      g = fminf(fmaxf(g, 0.f), 1.f);
      float cc = constants[l*L_ + c];
      a += (1.f - g) * cc * cc;
    }
    Ag[l] = a;
  }
}

// ---------------------------------------------------------------- K12 v10:
// NO LDS x-TILE, NO DMA, NO BARRIERS. Ten rounds showed every
// global->LDS choreography (drained, counted, decoupled, flattened)
// pins k12 at 70-78us full-work with VALUBusy <=50%. The LDS tile
// existed only to remap x between score (lane=row) and accum
// (lane=colgroup) — but BOTH mappings load directly from global with
// good locality:
//   score: lane=row streams its 256-B row; each 64-B line is reused by
//          4 consecutive c-iters (L1); 4 waves share the block's 32 KB
//          in one CU's L1.
//   accum: lane (cg,rs) reads x[w][cg*4..+3] — each instr touches 4
//          full rows (4x256 B), perfectly coalesced; L1/L2-hot re-read.
// Only the wave-local e-exchange stays in LDS (es, 4 KB/block).
// Ordinary register loads -> the compiler software-pipelines with
// counted waitcnts itself; no manual vmcnt, no s_barrier anywhere.
// __launch_bounds__(256,4): 64-VGPR cap -> up to 32 waves/CU (8 blocks)
// — loop-free body est. ~50 live VGPR (r6's spill was the loop-carried
// dbuf version; v8/r9 ran the same cap on a similar body without blowup).
//
// Wave owns j-pair {2wv,2wv+1} end-to-end; grid (B,8), 128 rows/block;
// coverage: 8*128 = 1024 = W ✓ (r7/r8 half-coverage bug fixed in r10,
// kept fixed here; harness cannot catch it — output is identically 0
// since conf=exp(-~224) underflows f32 — so coverage is maintained by
// construction and checked via FETCH_SIZE ~>= 65 MB).
__global__ __launch_bounds__(256, 4) void k12_fused(const float* __restrict__ wm,
    const float* __restrict__ wcg, const float* __restrict__ w1g,
    const float* __restrict__ Ag, float* __restrict__ bpart, float* __restrict__ stats)
{
  __shared__ __align__(16) float es[4][128 * 2];   // 4 KB; per-wave scratch only

  const int tid = threadIdx.x;
  const int b = blockIdx.x, h = blockIdx.y;
  const int lane = tid & 63;
  const int wvu = __builtin_amdgcn_readfirstlane(tid >> 6);  // wave id (uniform)
  const int j0  = wvu * 2;                                   // this wave's j-pair
  const int cg = lane & 15, rs = lane >> 4;                  // accum mapping

  const float* wmb = wm + (size_t)b * (W_*L_) + (size_t)h * (128*L_);

  // ---- score: lane owns rows {lane, 64+lane}; stream straight from global
  float a10A = 0.f, a11A = 0.f, a20A = 0.f, a21A = 0.f;
  float a10B = 0.f, a11B = 0.f, a20B = 0.f, a21B = 0.f;
  const float* rowA = wmb + lane * 64;
  const float* rowB = wmb + (64 + lane) * 64;
  #pragma unroll
  for (int c = 0; c < 16; ++c) {
    float4 xA = *(const float4*)(rowA + c*4);
    float4 xB = *(const float4*)(rowB + c*4);
    float4 wc0 = *(const float4*)(wcg + (j0  )*L_ + c*4);   // uniform -> s_load
    float4 wc1 = *(const float4*)(wcg + (j0+1)*L_ + c*4);
    float4 w10 = *(const float4*)(w1g + (j0  )*L_ + c*4);
    float4 w11 = *(const float4*)(w1g + (j0+1)*L_ + c*4);
    float4 qA, qB;
    qA.x = xA.x*xA.x; qA.y = xA.y*xA.y; qA.z = xA.z*xA.z; qA.w = xA.w*xA.w;
    qB.x = xB.x*xB.x; qB.y = xB.y*xB.y; qB.z = xB.z*xB.z; qB.w = xB.w*xB.w;
    a10A = fmaf(wc0.x, xA.x, a10A); a10A = fmaf(wc0.y, xA.y, a10A);
    a10A = fmaf(wc0.z, xA.z, a10A); a10A = fmaf(wc0.w, xA.w, a10A);
    a11A = fmaf(wc1.x, xA.x, a11A); a11A = fmaf(wc1.y, xA.y, a11A);
    a11A = fmaf(wc1.z, xA.z, a11A); a11A = fmaf(wc1.w, xA.w, a11A);
    a20A = fmaf(w10.x, qA.x, a20A); a20A = fmaf(w10.y, qA.y, a20A);
    a20A = fmaf(w10.z, qA.z, a20A); a20A = fmaf(w10.w, qA.w, a20A);
    a21A = fmaf(w11.x, qA.x, a21A); a21A = fmaf(w11.y, qA.y, a21A);
    a21A = fmaf(w11.z, qA.z, a21A); a21A = fmaf(w11.w, qA.w, a21A);
    a10B = fmaf(wc0.x, xB.x, a10B); a10B = fmaf(wc0.y, xB.y, a10B);
    a10B = fmaf(wc0.z, xB.z, a10B); a10B = fmaf(wc0.w, xB.w, a10B);
    a11B = fmaf(wc1.x, xB.x, a11B); a11B = fmaf(wc1.y, xB.y, a11B);
    a11B = fmaf(wc1.z, xB.z, a11B); a11B = fmaf(wc1.w, xB.w, a11B);
    a20B = fmaf(w10.x, qB.x, a20B); a20B = fmaf(w10.y, qB.y, a20B);
    a20B = fmaf(w10.z, qB.z, a20B); a20B = fmaf(w10.w, qB.w, a20B);
    a21B = fmaf(w11.x, qB.x, a21B); a21B = fmaf(w11.y, qB.y, a21B);
    a21B = fmaf(w11.z, qB.z, a21B); a21B = fmaf(w11.w, qB.w, a21B);
  }
  float s0A = Ag[j0]   + a10A + a20A;   // wcg already holds -2*w1*c
  float s1A = Ag[j0+1] + a11A + a21A;
  float s0B = Ag[j0]   + a10B + a20B;
  float s1B = Ag[j0+1] + a11B + a21B;

  // stabilizer: min over this block's 128 rows (pure wave-reduce)
  float mn0 = fminf(s0A, s0B), mn1 = fminf(s1A, s1B);
  #pragma unroll
  for (int off = 1; off < 64; off <<= 1) {
    mn0 = fminf(mn0, __shfl_xor(mn0, off));
    mn1 = fminf(mn1, __shfl_xor(mn1, off));
  }

  float e0A = __expf(mn0 - s0A), e1A = __expf(mn1 - s1A);
  float e0B = __expf(mn0 - s0B), e1B = __expf(mn1 - s1B);
  // wave-local publish (rows lane and 64+lane); lgkm drain, NO barrier
  *(float2*)&es[wvu][lane*2]        = make_float2(e0A, e1A);
  *(float2*)&es[wvu][(64 + lane)*2] = make_float2(e0B, e1B);
  asm volatile("s_waitcnt lgkmcnt(0)" ::: "memory");

  // ---- accum: lane (cg, rs) accumulates best[j0/j0+1][cg*4..+3] over
  //      rows w = rs*32 .. rs*32+31, re-reading x from global (L1/L2-hot)
  const float* colp = wmb + cg*4;
  float acc0[4] = {0.f, 0.f, 0.f, 0.f};
  float acc1[4] = {0.f, 0.f, 0.f, 0.f};
  #pragma unroll
  for (int it = 0; it < 32; it += 2) {
    const int w0 = rs*32 + it;
    float4 e4 = *(const float4*)&es[wvu][w0*2];     // e0,e1 of w0,w0+1 (broadcast)
    float4 xA = *(const float4*)(colp + (size_t)w0*64);
    float4 xB = *(const float4*)(colp + (size_t)(w0+1)*64);
    acc0[0] = fmaf(e4.x, xA.x, acc0[0]); acc0[1] = fmaf(e4.x, xA.y, acc0[1]);
    acc0[2] = fmaf(e4.x, xA.z, acc0[2]); acc0[3] = fmaf(e4.x, xA.w, acc0[3]);
    acc1[0] = fmaf(e4.y, xA.x, acc1[0]); acc1[1] = fmaf(e4.y, xA.y, acc1[1]);
    acc1[2] = fmaf(e4.y, xA.z, acc1[2]); acc1[3] = fmaf(e4.y, xA.w, acc1[3]);
    acc0[0] = fmaf(e4.z, xB.x, acc0[0]); acc0[1] = fmaf(e4.z, xB.y, acc0[1]);
    acc0[2] = fmaf(e4.z, xB.z, acc0[2]); acc0[3] = fmaf(e4.z, xB.w, acc0[3]);
    acc1[0] = fmaf(e4.w, xB.x, acc1[0]); acc1[1] = fmaf(e4.w, xB.y, acc1[1]);
    acc1[2] = fmaf(e4.w, xB.z, acc1[2]); acc1[3] = fmaf(e4.w, xB.w, acc1[3]);
  }

  // ---- stats: reduce e and e*s over the block's 128 rows, lane 0 writes
  {
    float ea = e0A + e0B;
    float ma = fmaf(e0A, s0A, e0B * s0B);
    float eb = e1A + e1B;
    float mb = fmaf(e1A, s1A, e1B * s1B);
    #pragma unroll
    for (int off = 1; off < 64; off <<= 1) {
      ea += __shfl_xor(ea, off); ma += __shfl_xor(ma, off);
      eb += __shfl_xor(eb, off); mb += __shfl_xor(mb, off);
    }
    if (lane == 0) {
      float* st0 = stats + (((size_t)h*B_ + b)*J_ + j0)*4;
      st0[0] = mn0; st0[1] = ea; st0[2] = ma;
      float* st1 = stats + (((size_t)h*B_ + b)*J_ + j0 + 1)*4;
      st1[0] = mn1; st1[1] = eb; st1[2] = mb;
    }
  }

  // ---- epilogue: fold the 4 row-quarters (rs) — pure shuffle, no LDS
  #pragma unroll
  for (int q = 0; q < 4; ++q) {
    acc0[q] += __shfl_xor(acc0[q], 16);
    acc0[q] += __shfl_xor(acc0[q], 32);
    acc1[q] += __shfl_xor(acc1[q], 16);
    acc1[q] += __shfl_xor(acc1[q], 32);
  }
  if (lane < 16) {   // lane == cg
    float* bp0 = &bpart[(((size_t)h*J_ + j0    )*B_ + b)*L_ + cg*4];
    float* bp1 = &bpart[(((size_t)h*J_ + j0 + 1)*B_ + b)*L_ + cg*4];
    *(float4*)bp0 = make_float4(acc0[0], acc0[1], acc0[2], acc0[3]);
    *(float4*)bp1 = make_float4(acc1[0], acc1[1], acc1[2], acc1[3]);
  }
}

// ---------------------------------------------------------------- K2b: combine H_ partials
__global__ __launch_bounds__(128) void k2b_combine(const float* __restrict__ bpart,
    const float* __restrict__ stats, float* __restrict__ best, float* __restrict__ conf)
{
  __shared__ float mred[J_];
  const int b = blockIdx.x, tid = threadIdx.x;
  const int j = tid >> 4, q = tid & 15;

  float m0[H_], E[H_], Mq[H_];
  #pragma unroll
  for (int u = 0; u < H_; ++u) {
    const float* st = stats + (((size_t)u*B_ + b)*J_ + j)*4;
    m0[u] = st[0]; E[u] = st[1]; Mq[u] = st[2];
  }
  float M = m0[0];
  #pragma unroll
  for (int u = 1; u < H_; ++u) M = fminf(M, m0[u]);
  float s[H_], Esum = 0.f, Msum = 0.f;
  #pragma unroll
  for (int u = 0; u < H_; ++u) {
    s[u] = __expf(M - m0[u]);
    Esum = fmaf(s[u], E[u], Esum);
    Msum = fmaf(s[u], Mq[u], Msum);
  }
  float inv = 1.f / Esum;
  float4 o = make_float4(0.f, 0.f, 0.f, 0.f);
  #pragma unroll
  for (int u = 0; u < H_; ++u) {
    float4 p = *(const float4*)&bpart[(((size_t)u*J_ + j)*B_ + b)*L_ + q*4];
    o.x = fmaf(s[u], p.x, o.x); o.y = fmaf(s[u], p.y, o.y);
    o.z = fmaf(s[u], p.z, o.z); o.w = fmaf(s[u], p.w, o.w);
  }
  o.x *= inv; o.y *= inv; o.z *= inv; o.w *= inv;
  *(float4*)&best[((size_t)j*B_ + b)*L_ + q*4] = o;
  if (q == 0) mred[j] = Msum * inv;
  __syncthreads();
  if (tid == 0) {
    float mq = 0.f;
    #pragma unroll
    for (int jj = 0; jj < J_; ++jj) mq += mred[jj];
    conf[b] = __expf(-mq);
  }
}

// ---------------------------------------------------------------- K3: slot path, 4-way b ILP, no max-stabilizer
__global__ __launch_bounds__(256) void k3_slot(const float* __restrict__ slot_w,
    const float* __restrict__ slot_b, const float* __restrict__ best,
    float* __restrict__ partial)
{
  const int bx = blockIdx.y;            // (j, lgroup)
  const int j = bx >> 3, lg = bx & 7;
  const int bc = blockIdx.x;            // b-chunk fast dim -> L2 reuse
  const int tid = threadIdx.x;
  const int wv = tid >> 6, lane = tid & 63;
  const int l2 = lane >> 5, i = lane & 31;
  const int l = lg*8 + wv*2 + l2;
  const int r = l*I_ + i;

  const float* swr = slot_w + ((size_t)j*(L_*I_) + r) * L_;
  float sw[L_];
  #pragma unroll
  for (int c = 0; c < 16; ++c) {
    float4 t = ((const float4*)swr)[c];
    sw[c*4+0] = t.x; sw[c*4+1] = t.y; sw[c*4+2] = t.z; sw[c*4+3] = t.w;
  }
  const float sb = slot_b[j*(L_*I_) + r];
  const float* bestj = best + (size_t)j * B_ * L_;
  float* pout = partial + (size_t)bx * (B_*I_);
  const int lidx = lg*8 + wv*2;

  for (int bi = 0; bi < 32; bi += 4) {
    const int b0 = bc*32 + bi;
    const float* bw[4];
    #pragma unroll
    for (int u = 0; u < 4; ++u) bw[u] = bestj + (size_t)(b0+u) * L_;  // uniform -> s_load
    float pa[4], pb[4];
    #pragma unroll
    for (int u = 0; u < 4; ++u) { pa[u] = sb; pb[u] = 0.f; }
    #pragma unroll
    for (int c = 0; c < L_; c += 2) {
      #pragma unroll
      for (int u = 0; u < 4; ++u) {
        pa[u] = fmaf(bw[u][c+0], sw[c+0], pa[u]);
        pb[u] = fmaf(bw[u][c+1], sw[c+1], pb[u]);
      }
    }
    float e[4], sm[4];
    #pragma unroll
    for (int u = 0; u < 4; ++u) { e[u] = __expf(pa[u] + pb[u]); sm[u] = e[u]; }
    #pragma unroll
    for (int mask = 16; mask; mask >>= 1)
      #pragma unroll
      for (int u = 0; u < 4; ++u) sm[u] += __shfl_xor(sm[u], mask);
    float cv[4];
    #pragma unroll
    for (int u = 0; u < 4; ++u) {
      float bv = l2 ? bw[u][lidx+1] : bw[u][lidx];
      cv[u] = (e[u] / sm[u]) * bv;
    }
    #pragma unroll
    for (int u = 0; u < 4; ++u) cv[u] += __shfl_xor(cv[u], 32);
    if (l2 == 0) {
      #pragma unroll
      for (int u = 0; u < 4; ++u)
        pout[(size_t)(b0+u)*I_ + i] = cv[u];
    }
  }
}

// ---------------------------------------------------------------- K4: reduce + body + head + confidence
__global__ __launch_bounds__(128) void k4_head(const float* __restrict__ partial,
    const float* __restrict__ best, const float* __restrict__ gammas,
    const float* __restrict__ body_w, const float* __restrict__ body_b,
    const float* __restrict__ head_w, const float* __restrict__ head_b,
    const float* __restrict__ conf, float* __restrict__ out)
{
  __shared__ float gavg[J_];
  __shared__ float cvred[4][I_];
  __shared__ float cvf[I_];
  const int b = blockIdx.x, tid = threadIdx.x;
  const int i = tid & 31, q = tid >> 5;
  if (tid < J_) {
    float gsum = 0.f;
    for (int l = 0; l < L_; ++l) {
      float g = gammas[tid*L_ + l];
      gsum += fminf(fmaxf(g, 0.f), 1.f);
    }
    gavg[tid] = gsum * (1.f / L_);
  }
  __syncthreads();

  float acc = 0.f;
  for (int s = q; s < 64; s += 4)
    acc += partial[((size_t)s*B_ + b)*I_ + i];

  #pragma unroll
  for (int u = 0; u < 2; ++u) {
    const int j = q + u*4;
    const float* bwv  = best + ((size_t)j*B_ + b)*L_;
    const float* wrow = body_w + (size_t)(j*I_ + i)*L_;
    float d0 = body_b[j*I_ + i], d1 = 0.f, d2 = 0.f, d3 = 0.f;
    #pragma unroll
    for (int c = 0; c < L_; c += 4) {
      d0 = fmaf(bwv[c+0], wrow[c+0], d0);
      d1 = fmaf(bwv[c+1], wrow[c+1], d1);
      d2 = fmaf(bwv[c+2], wrow[c+2], d2);
      d3 = fmaf(bwv[c+3], wrow[c+3], d3);
    }
    acc = fmaf(gavg[j], (d0 + d1) + (d2 + d3), acc);
  }
  cvred[q][i] = acc;
  __syncthreads();
  if (tid < I_)
    cvf[i] = cvred[0][i] + cvred[1][i] + cvred[2][i] + cvred[3][i];
  __syncthreads();
  float oacc = head_b[tid];
  #pragma unroll
  for (int i2 = 0; i2 < I_; ++i2) oacc = fmaf(cvf[i2], head_w[tid*I_ + i2], oacc);
  out[(size_t)b*O_ + tid] = conf[b] * oacc;
}

extern "C" void kernel_launch(void* const* d_in, const int* in_sizes, int n_in,
                              void* d_out, int out_size, void* d_ws, size_t ws_size,
                              hipStream_t stream) {
  const float* wm        = (const float*)d_in[0];
  const float* constants = (const float*)d_in[1];
  const float* gammas    = (const float*)d_in[2];
  const float* body_w    = (const float*)d_in[3];
  const float* body_b    = (const float*)d_in[4];
  const float* slot_w    = (const float*)d_in[5];
  const float* slot_b    = (const float*)d_in[6];
  const float* head_w    = (const float*)d_in[7];
  const float* head_b    = (const float*)d_in[8];
  float* out = (float*)d_out;

  float* ws      = (float*)d_ws;
  float* wcg     = ws;
  float* w1g     = wcg + J_*L_;
  float* Ag      = w1g + J_*L_;
  float* best    = Ag + 16;
  float* conf    = best + (size_t)J_*B_*L_;
  float* partial = conf + B_;
  float* bpart   = partial + (size_t)64*B_*I_;
  float* stats   = bpart + (size_t)H_*J_*B_*L_;

  hipLaunchKernelGGL(k0_prep, dim3(1), dim3(64), 0, stream,
                     constants, gammas, wcg, w1g, Ag);
  hipLaunchKernelGGL(k12_fused, dim3(B_, H_), dim3(256), 0, stream,
                     wm, wcg, w1g, Ag, bpart, stats);
  hipLaunchKernelGGL(k2b_combine, dim3(B_), dim3(128), 0, stream,
                     bpart, stats, best, conf);
  hipLaunchKernelGGL(k3_slot, dim3(16, 64), dim3(256), 0, stream,
                     slot_w, slot_b, best, partial);
  hipLaunchKernelGGL(k4_head, dim3(B_), dim3(128), 0, stream,
                     partial, best, gammas, body_w, body_b, head_w, head_b, conf, out);
}

// Round 12
// 315.054 us; speedup vs baseline: 1.3356x; 1.3356x over previous
//
#include <hip/hip_runtime.h>
#include <cstdint>
#include <cstddef>

#define B_ 512
#define W_ 1024
#define L_ 64
#define J_ 8
#define I_ 32
#define O_ 128
#define H_ 8            // wm split: 8 blocks of 128 rows each (8*128 = 1024 = W ✓)

// ws layout (floats):
// wcg   : [J][L]        = 512   (holds -2*(1-g)*c)
// w1g   : [J][L]        = 512
// Ag    : [J] (+pad)    = 16
// best  : [J][B][L]     = 262144
// conf  : [B]           = 512
// partial:[64][B][I]    = 1048576
// bpart : [H][J][B][L]  = 2097152
// stats : [H][B][J][4]  = 65536

// ---------------------------------------------------------------- K0
__global__ __launch_bounds__(64) void k0_prep(const float* __restrict__ constants,
    const float* __restrict__ gammas, float* __restrict__ wcg,
    float* __restrict__ w1g, float* __restrict__ Ag)
{
  const int l = threadIdx.x;
  #pragma unroll
  for (int j = 0; j < J_; ++j) {
    float g = gammas[j*L_ + l];
    g = fminf(fmaxf(g, 0.f), 1.f);
    float c = constants[j*L_ + l];
    float w1 = 1.f - g;
    w1g[j*L_ + l] = w1;
    wcg[j*L_ + l] = -2.f * w1 * c;   // fold the -2 of the cross term here
  }
  if (l < J_) {
    float a = 0.f;
    for (int c = 0; c < L_; ++c) {
      float g = gammas[l*L_ + c];
      g = fminf(fmaxf(g, 0.f), 1.f);
      float cc = constants[l*L_ + c];
      a += (1.f - g) * cc * cc;
    }
    Ag[l] = a;
  }
}

// ---------------------------------------------------------------- K12 v10b:
// v10 (no LDS x-tile, no DMA, no barriers — both phases read x straight
// from global; only the 4 KB wave-local es survives in LDS) with the
// register cap REPAIRED. r11's __launch_bounds__(256,4) forced 64 VGPR
// against a ~90+ live body (8 score accums + 2 rows x + q temporaries)
// -> 381 MB scratch writes, k12 218us. Third cap-induced spill (r6,
// r11): rule — never cap below the previous variant's measured natural
// VGPR. (256,2) allows up to 128 VGPR: no spill, 4 blocks/CU (16
// waves), and with ZERO sync in the body waves never wait on each
// other — the compiler pipelines the plain global loads itself.
//
//   score: lane owns rows {lane, 64+lane}; each 64-B line is consumed
//          across 4 consecutive c-iters (L1-resident).
//   accum: lane (cg,rs) reads x[w][cg*4..+3] — 1 KB/instruction fully
//          coalesced; re-read ~1us after first read -> L2-hot
//          (block working set 32 KB; ~256 KB co-resident vs 4 MB L2).
//
// Wave owns j-pair {2wv,2wv+1} end-to-end; grid (B,8), 128 rows/block;
// coverage 8*128 = 1024 = W ✓ (r7/r8 half-coverage bug stays fixed;
// the harness cannot catch coverage loss — output is identically 0
// because conf=exp(-~224) underflows f32 — so coverage is maintained
// by construction and audited via FETCH_SIZE >= ~134 MB).
__global__ __launch_bounds__(256, 2) void k12_fused(const float* __restrict__ wm,
    const float* __restrict__ wcg, const float* __restrict__ w1g,
    const float* __restrict__ Ag, float* __restrict__ bpart, float* __restrict__ stats)
{
  __shared__ __align__(16) float es[4][128 * 2];   // 4 KB; per-wave scratch only

  const int tid = threadIdx.x;
  const int b = blockIdx.x, h = blockIdx.y;
  const int lane = tid & 63;
  const int wvu = __builtin_amdgcn_readfirstlane(tid >> 6);  // wave id (uniform)
  const int j0  = wvu * 2;                                   // this wave's j-pair
  const int cg = lane & 15, rs = lane >> 4;                  // accum mapping

  const float* wmb = wm + (size_t)b * (W_*L_) + (size_t)h * (128*L_);

  // ---- score: lane owns rows {lane, 64+lane}; stream straight from global
  float a10A = 0.f, a11A = 0.f, a20A = 0.f, a21A = 0.f;
  float a10B = 0.f, a11B = 0.f, a20B = 0.f, a21B = 0.f;
  const float* rowA = wmb + lane * 64;
  const float* rowB = wmb + (64 + lane) * 64;
  #pragma unroll
  for (int c = 0; c < 16; ++c) {
    float4 xA = *(const float4*)(rowA + c*4);
    float4 xB = *(const float4*)(rowB + c*4);
    float4 wc0 = *(const float4*)(wcg + (j0  )*L_ + c*4);   // uniform -> s_load
    float4 wc1 = *(const float4*)(wcg + (j0+1)*L_ + c*4);
    float4 w10 = *(const float4*)(w1g + (j0  )*L_ + c*4);
    float4 w11 = *(const float4*)(w1g + (j0+1)*L_ + c*4);
    float4 qA, qB;
    qA.x = xA.x*xA.x; qA.y = xA.y*xA.y; qA.z = xA.z*xA.z; qA.w = xA.w*xA.w;
    qB.x = xB.x*xB.x; qB.y = xB.y*xB.y; qB.z = xB.z*xB.z; qB.w = xB.w*xB.w;
    a10A = fmaf(wc0.x, xA.x, a10A); a10A = fmaf(wc0.y, xA.y, a10A);
    a10A = fmaf(wc0.z, xA.z, a10A); a10A = fmaf(wc0.w, xA.w, a10A);
    a11A = fmaf(wc1.x, xA.x, a11A); a11A = fmaf(wc1.y, xA.y, a11A);
    a11A = fmaf(wc1.z, xA.z, a11A); a11A = fmaf(wc1.w, xA.w, a11A);
    a20A = fmaf(w10.x, qA.x, a20A); a20A = fmaf(w10.y, qA.y, a20A);
    a20A = fmaf(w10.z, qA.z, a20A); a20A = fmaf(w10.w, qA.w, a20A);
    a21A = fmaf(w11.x, qA.x, a21A); a21A = fmaf(w11.y, qA.y, a21A);
    a21A = fmaf(w11.z, qA.z, a21A); a21A = fmaf(w11.w, qA.w, a21A);
    a10B = fmaf(wc0.x, xB.x, a10B); a10B = fmaf(wc0.y, xB.y, a10B);
    a10B = fmaf(wc0.z, xB.z, a10B); a10B = fmaf(wc0.w, xB.w, a10B);
    a11B = fmaf(wc1.x, xB.x, a11B); a11B = fmaf(wc1.y, xB.y, a11B);
    a11B = fmaf(wc1.z, xB.z, a11B); a11B = fmaf(wc1.w, xB.w, a11B);
    a20B = fmaf(w10.x, qB.x, a20B); a20B = fmaf(w10.y, qB.y, a20B);
    a20B = fmaf(w10.z, qB.z, a20B); a20B = fmaf(w10.w, qB.w, a20B);
    a21B = fmaf(w11.x, qB.x, a21B); a21B = fmaf(w11.y, qB.y, a21B);
    a21B = fmaf(w11.z, qB.z, a21B); a21B = fmaf(w11.w, qB.w, a21B);
  }
  float s0A = Ag[j0]   + a10A + a20A;   // wcg already holds -2*w1*c
  float s1A = Ag[j0+1] + a11A + a21A;
  float s0B = Ag[j0]   + a10B + a20B;
  float s1B = Ag[j0+1] + a11B + a21B;

  // stabilizer: min over this block's 128 rows (pure wave-reduce)
  float mn0 = fminf(s0A, s0B), mn1 = fminf(s1A, s1B);
  #pragma unroll
  for (int off = 1; off < 64; off <<= 1) {
    mn0 = fminf(mn0, __shfl_xor(mn0, off));
    mn1 = fminf(mn1, __shfl_xor(mn1, off));
  }

  float e0A = __expf(mn0 - s0A), e1A = __expf(mn1 - s1A);
  float e0B = __expf(mn0 - s0B), e1B = __expf(mn1 - s1B);
  // wave-local publish (rows lane and 64+lane); lgkm drain, NO barrier
  *(float2*)&es[wvu][lane*2]        = make_float2(e0A, e1A);
  *(float2*)&es[wvu][(64 + lane)*2] = make_float2(e0B, e1B);
  asm volatile("s_waitcnt lgkmcnt(0)" ::: "memory");

  // ---- accum: lane (cg, rs) accumulates best[j0/j0+1][cg*4..+3] over
  //      rows w = rs*32 .. rs*32+31, re-reading x from global (L1/L2-hot)
  const float* colp = wmb + cg*4;
  float acc0[4] = {0.f, 0.f, 0.f, 0.f};
  float acc1[4] = {0.f, 0.f, 0.f, 0.f};
  #pragma unroll
  for (int it = 0; it < 32; it += 2) {
    const int w0 = rs*32 + it;
    float4 e4 = *(const float4*)&es[wvu][w0*2];     // e0,e1 of w0,w0+1 (broadcast)
    float4 xA = *(const float4*)(colp + (size_t)w0*64);
    float4 xB = *(const float4*)(colp + (size_t)(w0+1)*64);
    acc0[0] = fmaf(e4.x, xA.x, acc0[0]); acc0[1] = fmaf(e4.x, xA.y, acc0[1]);
    acc0[2] = fmaf(e4.x, xA.z, acc0[2]); acc0[3] = fmaf(e4.x, xA.w, acc0[3]);
    acc1[0] = fmaf(e4.y, xA.x, acc1[0]); acc1[1] = fmaf(e4.y, xA.y, acc1[1]);
    acc1[2] = fmaf(e4.y, xA.z, acc1[2]); acc1[3] = fmaf(e4.y, xA.w, acc1[3]);
    acc0[0] = fmaf(e4.z, xB.x, acc0[0]); acc0[1] = fmaf(e4.z, xB.y, acc0[1]);
    acc0[2] = fmaf(e4.z, xB.z, acc0[2]); acc0[3] = fmaf(e4.z, xB.w, acc0[3]);
    acc1[0] = fmaf(e4.w, xB.x, acc1[0]); acc1[1] = fmaf(e4.w, xB.y, acc1[1]);
    acc1[2] = fmaf(e4.w, xB.z, acc1[2]); acc1[3] = fmaf(e4.w, xB.w, acc1[3]);
  }

  // ---- stats: reduce e and e*s over the block's 128 rows, lane 0 writes
  {
    float ea = e0A + e0B;
    float ma = fmaf(e0A, s0A, e0B * s0B);
    float eb = e1A + e1B;
    float mb = fmaf(e1A, s1A, e1B * s1B);
    #pragma unroll
    for (int off = 1; off < 64; off <<= 1) {
      ea += __shfl_xor(ea, off); ma += __shfl_xor(ma, off);
      eb += __shfl_xor(eb, off); mb += __shfl_xor(mb, off);
    }
    if (lane == 0) {
      float* st0 = stats + (((size_t)h*B_ + b)*J_ + j0)*4;
      st0[0] = mn0; st0[1] = ea; st0[2] = ma;
      float* st1 = stats + (((size_t)h*B_ + b)*J_ + j0 + 1)*4;
      st1[0] = mn1; st1[1] = eb; st1[2] = mb;
    }
  }

  // ---- epilogue: fold the 4 row-quarters (rs) — pure shuffle, no LDS
  #pragma unroll
  for (int q = 0; q < 4; ++q) {
    acc0[q] += __shfl_xor(acc0[q], 16);
    acc0[q] += __shfl_xor(acc0[q], 32);
    acc1[q] += __shfl_xor(acc1[q], 16);
    acc1[q] += __shfl_xor(acc1[q], 32);
  }
  if (lane < 16) {   // lane == cg
    float* bp0 = &bpart[(((size_t)h*J_ + j0    )*B_ + b)*L_ + cg*4];
    float* bp1 = &bpart[(((size_t)h*J_ + j0 + 1)*B_ + b)*L_ + cg*4];
    *(float4*)bp0 = make_float4(acc0[0], acc0[1], acc0[2], acc0[3]);
    *(float4*)bp1 = make_float4(acc1[0], acc1[1], acc1[2], acc1[3]);
  }
}

// ---------------------------------------------------------------- K2b: combine H_ partials
__global__ __launch_bounds__(128) void k2b_combine(const float* __restrict__ bpart,
    const float* __restrict__ stats, float* __restrict__ best, float* __restrict__ conf)
{
  __shared__ float mred[J_];
  const int b = blockIdx.x, tid = threadIdx.x;
  const int j = tid >> 4, q = tid & 15;

  float m0[H_], E[H_], Mq[H_];
  #pragma unroll
  for (int u = 0; u < H_; ++u) {
    const float* st = stats + (((size_t)u*B_ + b)*J_ + j)*4;
    m0[u] = st[0]; E[u] = st[1]; Mq[u] = st[2];
  }
  float M = m0[0];
  #pragma unroll
  for (int u = 1; u < H_; ++u) M = fminf(M, m0[u]);
  float s[H_], Esum = 0.f, Msum = 0.f;
  #pragma unroll
  for (int u = 0; u < H_; ++u) {
    s[u] = __expf(M - m0[u]);
    Esum = fmaf(s[u], E[u], Esum);
    Msum = fmaf(s[u], Mq[u], Msum);
  }
  float inv = 1.f / Esum;
  float4 o = make_float4(0.f, 0.f, 0.f, 0.f);
  #pragma unroll
  for (int u = 0; u < H_; ++u) {
    float4 p = *(const float4*)&bpart[(((size_t)u*J_ + j)*B_ + b)*L_ + q*4];
    o.x = fmaf(s[u], p.x, o.x); o.y = fmaf(s[u], p.y, o.y);
    o.z = fmaf(s[u], p.z, o.z); o.w = fmaf(s[u], p.w, o.w);
  }
  o.x *= inv; o.y *= inv; o.z *= inv; o.w *= inv;
  *(float4*)&best[((size_t)j*B_ + b)*L_ + q*4] = o;
  if (q == 0) mred[j] = Msum * inv;
  __syncthreads();
  if (tid == 0) {
    float mq = 0.f;
    #pragma unroll
    for (int jj = 0; jj < J_; ++jj) mq += mred[jj];
    conf[b] = __expf(-mq);
  }
}

// ---------------------------------------------------------------- K3: slot path, 4-way b ILP, no max-stabilizer
__global__ __launch_bounds__(256) void k3_slot(const float* __restrict__ slot_w,
    const float* __restrict__ slot_b, const float* __restrict__ best,
    float* __restrict__ partial)
{
  const int bx = blockIdx.y;            // (j, lgroup)
  const int j = bx >> 3, lg = bx & 7;
  const int bc = blockIdx.x;            // b-chunk fast dim -> L2 reuse
  const int tid = threadIdx.x;
  const int wv = tid >> 6, lane = tid & 63;
  const int l2 = lane >> 5, i = lane & 31;
  const int l = lg*8 + wv*2 + l2;
  const int r = l*I_ + i;

  const float* swr = slot_w + ((size_t)j*(L_*I_) + r) * L_;
  float sw[L_];
  #pragma unroll
  for (int c = 0; c < 16; ++c) {
    float4 t = ((const float4*)swr)[c];
    sw[c*4+0] = t.x; sw[c*4+1] = t.y; sw[c*4+2] = t.z; sw[c*4+3] = t.w;
  }
  const float sb = slot_b[j*(L_*I_) + r];
  const float* bestj = best + (size_t)j * B_ * L_;
  float* pout = partial + (size_t)bx * (B_*I_);
  const int lidx = lg*8 + wv*2;

  for (int bi = 0; bi < 32; bi += 4) {
    const int b0 = bc*32 + bi;
    const float* bw[4];
    #pragma unroll
    for (int u = 0; u < 4; ++u) bw[u] = bestj + (size_t)(b0+u) * L_;  // uniform -> s_load
    float pa[4], pb[4];
    #pragma unroll
    for (int u = 0; u < 4; ++u) { pa[u] = sb; pb[u] = 0.f; }
    #pragma unroll
    for (int c = 0; c < L_; c += 2) {
      #pragma unroll
      for (int u = 0; u < 4; ++u) {
        pa[u] = fmaf(bw[u][c+0], sw[c+0], pa[u]);
        pb[u] = fmaf(bw[u][c+1], sw[c+1], pb[u]);
      }
    }
    float e[4], sm[4];
    #pragma unroll
    for (int u = 0; u < 4; ++u) { e[u] = __expf(pa[u] + pb[u]); sm[u] = e[u]; }
    #pragma unroll
    for (int mask = 16; mask; mask >>= 1)
      #pragma unroll
      for (int u = 0; u < 4; ++u) sm[u] += __shfl_xor(sm[u], mask);
    float cv[4];
    #pragma unroll
    for (int u = 0; u < 4; ++u) {
      float bv = l2 ? bw[u][lidx+1] : bw[u][lidx];
      cv[u] = (e[u] / sm[u]) * bv;
    }
    #pragma unroll
    for (int u = 0; u < 4; ++u) cv[u] += __shfl_xor(cv[u], 32);
    if (l2 == 0) {
      #pragma unroll
      for (int u = 0; u < 4; ++u)
        pout[(size_t)(b0+u)*I_ + i] = cv[u];
    }
  }
}

// ---------------------------------------------------------------- K4: reduce + body + head + confidence
__global__ __launch_bounds__(128) void k4_head(const float* __restrict__ partial,
    const float* __restrict__ best, const float* __restrict__ gammas,
    const float* __restrict__ body_w, const float* __restrict__ body_b,
    const float* __restrict__ head_w, const float* __restrict__ head_b,
    const float* __restrict__ conf, float* __restrict__ out)
{
  __shared__ float gavg[J_];
  __shared__ float cvred[4][I_];
  __shared__ float cvf[I_];
  const int b = blockIdx.x, tid = threadIdx.x;
  const int i = tid & 31, q = tid >> 5;
  if (tid < J_) {
    float gsum = 0.f;
    for (int l = 0; l < L_; ++l) {
      float g = gammas[tid*L_ + l];
      gsum += fminf(fmaxf(g, 0.f), 1.f);
    }
    gavg[tid] = gsum * (1.f / L_);
  }
  __syncthreads();

  float acc = 0.f;
  for (int s = q; s < 64; s += 4)
    acc += partial[((size_t)s*B_ + b)*I_ + i];

  #pragma unroll
  for (int u = 0; u < 2; ++u) {
    const int j = q + u*4;
    const float* bwv  = best + ((size_t)j*B_ + b)*L_;
    const float* wrow = body_w + (size_t)(j*I_ + i)*L_;
    float d0 = body_b[j*I_ + i], d1 = 0.f, d2 = 0.f, d3 = 0.f;
    #pragma unroll
    for (int c = 0; c < L_; c += 4) {
      d0 = fmaf(bwv[c+0], wrow[c+0], d0);
      d1 = fmaf(bwv[c+1], wrow[c+1], d1);
      d2 = fmaf(bwv[c+2], wrow[c+2], d2);
      d3 = fmaf(bwv[c+3], wrow[c+3], d3);
    }
    acc = fmaf(gavg[j], (d0 + d1) + (d2 + d3), acc);
  }
  cvred[q][i] = acc;
  __syncthreads();
  if (tid < I_)
    cvf[i] = cvred[0][i] + cvred[1][i] + cvred[2][i] + cvred[3][i];
  __syncthreads();
  float oacc = head_b[tid];
  #pragma unroll
  for (int i2 = 0; i2 < I_; ++i2) oacc = fmaf(cvf[i2], head_w[tid*I_ + i2], oacc);
  out[(size_t)b*O_ + tid] = conf[b] * oacc;
}

extern "C" void kernel_launch(void* const* d_in, const int* in_sizes, int n_in,
                              void* d_out, int out_size, void* d_ws, size_t ws_size,
                              hipStream_t stream) {
  const float* wm        = (const float*)d_in[0];
  const float* constants = (const float*)d_in[1];
  const float* gammas    = (const float*)d_in[2];
  const float* body_w    = (const float*)d_in[3];
  const float* body_b    = (const float*)d_in[4];
  const float* slot_w    = (const float*)d_in[5];
  const float* slot_b    = (const float*)d_in[6];
  const float* head_w    = (const float*)d_in[7];
  const float* head_b    = (const float*)d_in[8];
  float* out = (float*)d_out;

  float* ws      = (float*)d_ws;
  float* wcg     = ws;
  float* w1g     = wcg + J_*L_;
  float* Ag      = w1g + J_*L_;
  float* best    = Ag + 16;
  float* conf    = best + (size_t)J_*B_*L_;
  float* partial = conf + B_;
  float* bpart   = partial + (size_t)64*B_*I_;
  float* stats   = bpart + (size_t)H_*J_*B_*L_;

  hipLaunchKernelGGL(k0_prep, dim3(1), dim3(64), 0, stream,
                     constants, gammas, wcg, w1g, Ag);
  hipLaunchKernelGGL(k12_fused, dim3(B_, H_), dim3(256), 0, stream,
                     wm, wcg, w1g, Ag, bpart, stats);
  hipLaunchKernelGGL(k2b_combine, dim3(B_), dim3(128), 0, stream,
                     bpart, stats, best, conf);
  hipLaunchKernelGGL(k3_slot, dim3(16, 64), dim3(256), 0, stream,
                     slot_w, slot_b, best, partial);
  hipLaunchKernelGGL(k4_head, dim3(B_), dim3(128), 0, stream,
                     partial, best, gammas, body_w, body_b, head_w, head_b, conf, out);
}

// Round 13
// 273.282 us; speedup vs baseline: 1.5397x; 1.1529x over previous
//
#include <hip/hip_runtime.h>
#include <cstdint>
#include <cstddef>

#define B_ 512
#define W_ 1024
#define L_ 64
#define J_ 8
#define I_ 32
#define O_ 128
#define H_ 16           // wm split: 16 blocks of 64 rows each (16*64 = 1024 = W ✓)

// ws layout (floats):
// wcg   : [J][L]        = 512   (holds -2*(1-g)*c)
// w1g   : [J][L]        = 512
// Ag    : [J] (+pad)    = 16
// best  : [J][B][L]     = 262144
// conf  : [B]           = 512
// partial:[64][B][I]    = 1048576
// bpart : [H][J][B][L]  = 4194304  (16 MB)
// stats : [H][B][J][4]  = 262144   (1 MB)

typedef const __attribute__((address_space(1))) void* gas_ptr;
typedef __attribute__((address_space(3))) void* las_ptr;

// ---------------------------------------------------------------- K0
__global__ __launch_bounds__(64) void k0_prep(const float* __restrict__ constants,
    const float* __restrict__ gammas, float* __restrict__ wcg,
    float* __restrict__ w1g, float* __restrict__ Ag)
{
  const int l = threadIdx.x;
  #pragma unroll
  for (int j = 0; j < J_; ++j) {
    float g = gammas[j*L_ + l];
    g = fminf(fmaxf(g, 0.f), 1.f);
    float c = constants[j*L_ + l];
    float w1 = 1.f - g;
    w1g[j*L_ + l] = w1;
    wcg[j*L_ + l] = -2.f * w1 * c;   // fold the -2 of the cross term here
  }
  if (l < J_) {
    float a = 0.f;
    for (int c = 0; c < L_; ++c) {
      float g = gammas[l*L_ + c];
      g = fminf(fmaxf(g, 0.f), 1.f);
      float cc = constants[l*L_ + c];
      a += (1.f - g) * cc * cc;
    }
    Ag[l] = a;
  }
}

// ---------------------------------------------------------------- K12 v11:
// v8's PROVEN fast structure (r8/r9: 64-row LDS-staged blocks, (256,4)
// 64-VGPR no-spill, 51us) with COVERAGE FIXED via H_=16: grid (B,16),
// 16 x 64 = 1024 rows ✓. r7/r8's H_=8 silently dropped half of wm
// (undetectable: output is identically 0 — conf=exp(-~224) underflows
// f32 — so coverage is enforced by construction, audited via
// FETCH_SIZE ~66 MB).
//
// Consolidated model (13 data points): k12 dur ~= FETCH/~900 GB/s for
// every variant; the only sub-plateau point was v8's max-concurrency
// config (8 blocks/CU, most independent DMA streams). r12 falsified
// the no-LDS path (L1 thrash, 625 GB/s); LDS staging restored.
//
// Per block: stage its 64-row chunk (4 DMA/wave), one vmcnt(0)+barrier,
// wave owns j-pair {2wv,2wv+1} end-to-end: score (lane=row) -> e in
// wave-local es (lgkmcnt(0), no barrier) -> accum (cg=lane&15,
// rs=lane>>4, rows rs*16..+15) -> pure-shuffle epilogue. 0 bank
// conflicts (r6-verified). Swizzle: LDS[row][g] = global[row][g^(row&15)].
__global__ __launch_bounds__(256, 4) void k12_fused(const float* __restrict__ wm,
    const float* __restrict__ wcg, const float* __restrict__ w1g,
    const float* __restrict__ Ag, float* __restrict__ bpart, float* __restrict__ stats)
{
  __shared__ __align__(16) float xs[64 * 64];      // 16384 B
  __shared__ __align__(16) float es[4][64 * 2];    // 2048 B (per-wave scratch)

  const int tid = threadIdx.x;
  const int b = blockIdx.x, h = blockIdx.y;
  const int lane = tid & 63;
  const int wvu = __builtin_amdgcn_readfirstlane(tid >> 6);  // wave id (uniform)
  const int j0  = wvu * 2;                                   // this wave's j-pair
  const int wm15 = lane & 15;                                // score swizzle key (row&15)
  const int cg = lane & 15, rs = lane >> 4;                  // accum mapping
  const int rl = lane >> 4, pcg = lane & 15;                 // staging decomposition

  const float* wmb = wm + (size_t)b * (W_*L_) + (size_t)h * (64*L_);

  // ---- stage this block's 64-row chunk (one-time)
  #pragma unroll
  for (int k = 0; k < 4; ++k) {
    const int grow = wvu*16 + k*4 + rl;
    const int lcg  = pcg ^ (k*4 + rl);           // (grow&15) == k*4+rl
    __builtin_amdgcn_global_load_lds(
        (gas_ptr)(wmb + grow*64 + lcg*4),
        (las_ptr)&xs[(wvu*16 + k*4)*64], 16, 0, 0);
  }
  asm volatile("s_waitcnt vmcnt(0)" ::: "memory");
  __builtin_amdgcn_s_barrier();                  // the ONLY barrier

  // ---- score: lane owns row w=lane, wave owns j-pair
  float a10 = 0.f, a11 = 0.f, a20 = 0.f, a21 = 0.f;
  #pragma unroll
  for (int c = 0; c < 16; ++c) {
    const int col = c ^ wm15;
    float4 x = *(const float4*)&xs[lane*64 + col*4];
    float4 xq;
    xq.x = x.x*x.x; xq.y = x.y*x.y; xq.z = x.z*x.z; xq.w = x.w*x.w;
    float4 wc0 = *(const float4*)(wcg + (j0  )*L_ + c*4);   // scalar (j0 uniform)
    float4 wc1 = *(const float4*)(wcg + (j0+1)*L_ + c*4);
    float4 w10 = *(const float4*)(w1g + (j0  )*L_ + c*4);
    float4 w11 = *(const float4*)(w1g + (j0+1)*L_ + c*4);
    a10 = fmaf(wc0.x, x.x, a10); a10 = fmaf(wc0.y, x.y, a10);
    a10 = fmaf(wc0.z, x.z, a10); a10 = fmaf(wc0.w, x.w, a10);
    a11 = fmaf(wc1.x, x.x, a11); a11 = fmaf(wc1.y, x.y, a11);
    a11 = fmaf(wc1.z, x.z, a11); a11 = fmaf(wc1.w, x.w, a11);
    a20 = fmaf(w10.x, xq.x, a20); a20 = fmaf(w10.y, xq.y, a20);
    a20 = fmaf(w10.z, xq.z, a20); a20 = fmaf(w10.w, xq.w, a20);
    a21 = fmaf(w11.x, xq.x, a21); a21 = fmaf(w11.y, xq.y, a21);
    a21 = fmaf(w11.z, xq.z, a21); a21 = fmaf(w11.w, xq.w, a21);
  }
  float s0v = Ag[j0]   + a10 + a20;   // wcg already holds -2*w1*c
  float s1v = Ag[j0+1] + a11 + a21;

  // stabilizer: min over this block's 64 rows (pure wave-reduce)
  float mn0 = s0v, mn1 = s1v;
  #pragma unroll
  for (int off = 1; off < 64; off <<= 1) {
    mn0 = fminf(mn0, __shfl_xor(mn0, off));
    mn1 = fminf(mn1, __shfl_xor(mn1, off));
  }

  float e0 = __expf(mn0 - s0v);
  float e1 = __expf(mn1 - s1v);
  // wave-local publish: lane=row w writes (e0,e1) pair
  *(float2*)&es[wvu][lane*2] = make_float2(e0, e1);
  asm volatile("s_waitcnt lgkmcnt(0)" ::: "memory");   // wave-local, no barrier

  // ---- accum: lane (cg, rs) accumulates best[j0/j0+1][cg*4..+3]
  //      over rows w = rs*16 .. rs*16+15.
  float acc0[4] = {0.f, 0.f, 0.f, 0.f};
  float acc1[4] = {0.f, 0.f, 0.f, 0.f};
  #pragma unroll
  for (int it = 0; it < 16; it += 2) {
    const int w0 = rs*16 + it;
    float4 e4 = *(const float4*)&es[wvu][w0*2];     // e0,e1 of w0 and w0+1 (broadcast)
    float4 xA = *(const float4*)&xs[w0*64     + (cg ^ ( w0    & 15))*4];
    float4 xB = *(const float4*)&xs[(w0+1)*64 + (cg ^ ((w0+1) & 15))*4];
    acc0[0] = fmaf(e4.x, xA.x, acc0[0]); acc0[1] = fmaf(e4.x, xA.y, acc0[1]);
    acc0[2] = fmaf(e4.x, xA.z, acc0[2]); acc0[3] = fmaf(e4.x, xA.w, acc0[3]);
    acc1[0] = fmaf(e4.y, xA.x, acc1[0]); acc1[1] = fmaf(e4.y, xA.y, acc1[1]);
    acc1[2] = fmaf(e4.y, xA.z, acc1[2]); acc1[3] = fmaf(e4.y, xA.w, acc1[3]);
    acc0[0] = fmaf(e4.z, xB.x, acc0[0]); acc0[1] = fmaf(e4.z, xB.y, acc0[1]);
    acc0[2] = fmaf(e4.z, xB.z, acc0[2]); acc0[3] = fmaf(e4.z, xB.w, acc0[3]);
    acc1[0] = fmaf(e4.w, xB.x, acc1[0]); acc1[1] = fmaf(e4.w, xB.y, acc1[1]);
    acc1[2] = fmaf(e4.w, xB.z, acc1[2]); acc1[3] = fmaf(e4.w, xB.w, acc1[3]);
  }

  // ---- stats: reduce e and e*s over the wave's 64 rows, lane 0 writes
  {
    float ea = e0, ma = e0 * s0v, eb = e1, mb = e1 * s1v;
    #pragma unroll
    for (int off = 1; off < 64; off <<= 1) {
      ea += __shfl_xor(ea, off); ma += __shfl_xor(ma, off);
      eb += __shfl_xor(eb, off); mb += __shfl_xor(mb, off);
    }
    if (lane == 0) {
      float* st0 = stats + (((size_t)h*B_ + b)*J_ + j0)*4;
      st0[0] = mn0; st0[1] = ea; st0[2] = ma;
      float* st1 = stats + (((size_t)h*B_ + b)*J_ + j0 + 1)*4;
      st1[0] = mn1; st1[1] = eb; st1[2] = mb;
    }
  }

  // ---- epilogue: fold the 4 row-quarters (rs) — pure shuffle, no LDS
  #pragma unroll
  for (int q = 0; q < 4; ++q) {
    acc0[q] += __shfl_xor(acc0[q], 16);
    acc0[q] += __shfl_xor(acc0[q], 32);
    acc1[q] += __shfl_xor(acc1[q], 16);
    acc1[q] += __shfl_xor(acc1[q], 32);
  }
  if (lane < 16) {   // lane == cg
    float* bp0 = &bpart[(((size_t)h*J_ + j0    )*B_ + b)*L_ + cg*4];
    float* bp1 = &bpart[(((size_t)h*J_ + j0 + 1)*B_ + b)*L_ + cg*4];
    *(float4*)bp0 = make_float4(acc0[0], acc0[1], acc0[2], acc0[3]);
    *(float4*)bp1 = make_float4(acc1[0], acc1[1], acc1[2], acc1[3]);
  }
}

// ---------------------------------------------------------------- K2b: combine H_ partials
__global__ __launch_bounds__(128) void k2b_combine(const float* __restrict__ bpart,
    const float* __restrict__ stats, float* __restrict__ best, float* __restrict__ conf)
{
  __shared__ float mred[J_];
  const int b = blockIdx.x, tid = threadIdx.x;
  const int j = tid >> 4, q = tid & 15;

  float m0[H_], E[H_], Mq[H_];
  #pragma unroll
  for (int u = 0; u < H_; ++u) {
    const float* st = stats + (((size_t)u*B_ + b)*J_ + j)*4;
    m0[u] = st[0]; E[u] = st[1]; Mq[u] = st[2];
  }
  float M = m0[0];
  #pragma unroll
  for (int u = 1; u < H_; ++u) M = fminf(M, m0[u]);
  float s[H_], Esum = 0.f, Msum = 0.f;
  #pragma unroll
  for (int u = 0; u < H_; ++u) {
    s[u] = __expf(M - m0[u]);
    Esum = fmaf(s[u], E[u], Esum);
    Msum = fmaf(s[u], Mq[u], Msum);
  }
  float inv = 1.f / Esum;
  float4 o = make_float4(0.f, 0.f, 0.f, 0.f);
  #pragma unroll
  for (int u = 0; u < H_; ++u) {
    float4 p = *(const float4*)&bpart[(((size_t)u*J_ + j)*B_ + b)*L_ + q*4];
    o.x = fmaf(s[u], p.x, o.x); o.y = fmaf(s[u], p.y, o.y);
    o.z = fmaf(s[u], p.z, o.z); o.w = fmaf(s[u], p.w, o.w);
  }
  o.x *= inv; o.y *= inv; o.z *= inv; o.w *= inv;
  *(float4*)&best[((size_t)j*B_ + b)*L_ + q*4] = o;
  if (q == 0) mred[j] = Msum * inv;
  __syncthreads();
  if (tid == 0) {
    float mq = 0.f;
    #pragma unroll
    for (int jj = 0; jj < J_; ++jj) mq += mred[jj];
    conf[b] = __expf(-mq);
  }
}

// ---------------------------------------------------------------- K3: slot path, 4-way b ILP, no max-stabilizer
__global__ __launch_bounds__(256) void k3_slot(const float* __restrict__ slot_w,
    const float* __restrict__ slot_b, const float* __restrict__ best,
    float* __restrict__ partial)
{
  const int bx = blockIdx.y;            // (j, lgroup)
  const int j = bx >> 3, lg = bx & 7;
  const int bc = blockIdx.x;            // b-chunk fast dim -> L2 reuse
  const int tid = threadIdx.x;
  const int wv = tid >> 6, lane = tid & 63;
  const int l2 = lane >> 5, i = lane & 31;
  const int l = lg*8 + wv*2 + l2;
  const int r = l*I_ + i;

  const float* swr = slot_w + ((size_t)j*(L_*I_) + r) * L_;
  float sw[L_];
  #pragma unroll
  for (int c = 0; c < 16; ++c) {
    float4 t = ((const float4*)swr)[c];
    sw[c*4+0] = t.x; sw[c*4+1] = t.y; sw[c*4+2] = t.z; sw[c*4+3] = t.w;
  }
  const float sb = slot_b[j*(L_*I_) + r];
  const float* bestj = best + (size_t)j * B_ * L_;
  float* pout = partial + (size_t)bx * (B_*I_);
  const int lidx = lg*8 + wv*2;

  for (int bi = 0; bi < 32; bi += 4) {
    const int b0 = bc*32 + bi;
    const float* bw[4];
    #pragma unroll
    for (int u = 0; u < 4; ++u) bw[u] = bestj + (size_t)(b0+u) * L_;  // uniform -> s_load
    float pa[4], pb[4];
    #pragma unroll
    for (int u = 0; u < 4; ++u) { pa[u] = sb; pb[u] = 0.f; }
    #pragma unroll
    for (int c = 0; c < L_; c += 2) {
      #pragma unroll
      for (int u = 0; u < 4; ++u) {
        pa[u] = fmaf(bw[u][c+0], sw[c+0], pa[u]);
        pb[u] = fmaf(bw[u][c+1], sw[c+1], pb[u]);
      }
    }
    float e[4], sm[4];
    #pragma unroll
    for (int u = 0; u < 4; ++u) { e[u] = __expf(pa[u] + pb[u]); sm[u] = e[u]; }
    #pragma unroll
    for (int mask = 16; mask; mask >>= 1)
      #pragma unroll
      for (int u = 0; u < 4; ++u) sm[u] += __shfl_xor(sm[u], mask);
    float cv[4];
    #pragma unroll
    for (int u = 0; u < 4; ++u) {
      float bv = l2 ? bw[u][lidx+1] : bw[u][lidx];
      cv[u] = (e[u] / sm[u]) * bv;
    }
    #pragma unroll
    for (int u = 0; u < 4; ++u) cv[u] += __shfl_xor(cv[u], 32);
    if (l2 == 0) {
      #pragma unroll
      for (int u = 0; u < 4; ++u)
        pout[(size_t)(b0+u)*I_ + i] = cv[u];
    }
  }
}

// ---------------------------------------------------------------- K4: reduce + body + head + confidence
__global__ __launch_bounds__(128) void k4_head(const float* __restrict__ partial,
    const float* __restrict__ best, const float* __restrict__ gammas,
    const float* __restrict__ body_w, const float* __restrict__ body_b,
    const float* __restrict__ head_w, const float* __restrict__ head_b,
    const float* __restrict__ conf, float* __restrict__ out)
{
  __shared__ float gavg[J_];
  __shared__ float cvred[4][I_];
  __shared__ float cvf[I_];
  const int b = blockIdx.x, tid = threadIdx.x;
  const int i = tid & 31, q = tid >> 5;
  if (tid < J_) {
    float gsum = 0.f;
    for (int l = 0; l < L_; ++l) {
      float g = gammas[tid*L_ + l];
      gsum += fminf(fmaxf(g, 0.f), 1.f);
    }
    gavg[tid] = gsum * (1.f / L_);
  }
  __syncthreads();

  float acc = 0.f;
  for (int s = q; s < 64; s += 4)
    acc += partial[((size_t)s*B_ + b)*I_ + i];

  #pragma unroll
  for (int u = 0; u < 2; ++u) {
    const int j = q + u*4;
    const float* bwv  = best + ((size_t)j*B_ + b)*L_;
    const float* wrow = body_w + (size_t)(j*I_ + i)*L_;
    float d0 = body_b[j*I_ + i], d1 = 0.f, d2 = 0.f, d3 = 0.f;
    #pragma unroll
    for (int c = 0; c < L_; c += 4) {
      d0 = fmaf(bwv[c+0], wrow[c+0], d0);
      d1 = fmaf(bwv[c+1], wrow[c+1], d1);
      d2 = fmaf(bwv[c+2], wrow[c+2], d2);
      d3 = fmaf(bwv[c+3], wrow[c+3], d3);
    }
    acc = fmaf(gavg[j], (d0 + d1) + (d2 + d3), acc);
  }
  cvred[q][i] = acc;
  __syncthreads();
  if (tid < I_)
    cvf[i] = cvred[0][i] + cvred[1][i] + cvred[2][i] + cvred[3][i];
  __syncthreads();
  float oacc = head_b[tid];
  #pragma unroll
  for (int i2 = 0; i2 < I_; ++i2) oacc = fmaf(cvf[i2], head_w[tid*I_ + i2], oacc);
  out[(size_t)b*O_ + tid] = conf[b] * oacc;
}

extern "C" void kernel_launch(void* const* d_in, const int* in_sizes, int n_in,
                              void* d_out, int out_size, void* d_ws, size_t ws_size,
                              hipStream_t stream) {
  const float* wm        = (const float*)d_in[0];
  const float* constants = (const float*)d_in[1];
  const float* gammas    = (const float*)d_in[2];
  const float* body_w    = (const float*)d_in[3];
  const float* body_b    = (const float*)d_in[4];
  const float* slot_w    = (const float*)d_in[5];
  const float* slot_b    = (const float*)d_in[6];
  const float* head_w    = (const float*)d_in[7];
  const float* head_b    = (const float*)d_in[8];
  float* out = (float*)d_out;

  float* ws      = (float*)d_ws;
  float* wcg     = ws;
  float* w1g     = wcg + J_*L_;
  float* Ag      = w1g + J_*L_;
  float* best    = Ag + 16;
  float* conf    = best + (size_t)J_*B_*L_;
  float* partial = conf + B_;
  float* bpart   = partial + (size_t)64*B_*I_;
  float* stats   = bpart + (size_t)H_*J_*B_*L_;

  hipLaunchKernelGGL(k0_prep, dim3(1), dim3(64), 0, stream,
                     constants, gammas, wcg, w1g, Ag);
  hipLaunchKernelGGL(k12_fused, dim3(B_, H_), dim3(256), 0, stream,
                     wm, wcg, w1g, Ag, bpart, stats);
  hipLaunchKernelGGL(k2b_combine, dim3(B_), dim3(128), 0, stream,
                     bpart, stats, best, conf);
  hipLaunchKernelGGL(k3_slot, dim3(16, 64), dim3(256), 0, stream,
                     slot_w, slot_b, best, partial);
  hipLaunchKernelGGL(k4_head, dim3(B_), dim3(128), 0, stream,
                     partial, best, gammas, body_w, body_b, head_w, head_b, conf, out);
}